// Round 1
// baseline (51.078 us; speedup 1.0000x reference)
//
#include <hip/hip_runtime.h>
#include <math.h>

#define NB    2
#define L0    4800
#define L1    4800
#define H1C   60
#define W1C   80
#define ROWS  8          // rows per block
#define NBLK  (NB * L0 / ROWS)   // 1200

// ---------------------------------------------------------------------------
// Kernel 1: detect the storage format of the bool mask input.
// flag: 0 = int32 (words all in {0,1}), 1 = float32 (words in {0,0x3f800000}),
//       2 = uint8 (anything else).
// Scans 2400 words = 9600 bytes, which is within bounds for every candidate
// layout (uint8 buffer is exactly 9600 bytes).
// ---------------------------------------------------------------------------
__global__ __launch_bounds__(256) void detect_mask_kernel(
    const unsigned int* __restrict__ m, int* __restrict__ flag)
{
    __shared__ unsigned int sb, sc;
    if (threadIdx.x == 0) { sb = 0u; sc = 0u; }
    __syncthreads();
    unsigned int b = 0u, c = 0u;
    for (int i = threadIdx.x; i < 2400; i += 256) {
        unsigned int w = m[i];
        b |= (w & ~1u);             // nonzero => not all {0,1}
        c |= (w & ~0x3f800000u);    // nonzero => not all {0,1.0f}
    }
    atomicOr(&sb, b);
    atomicOr(&sc, c);
    __syncthreads();
    if (threadIdx.x == 0) {
        *flag = (sb == 0u) ? 0 : ((sc == 0u) ? 1 : 2);
    }
}

// ---------------------------------------------------------------------------
// Kernel 2: per-row min/argmin over L1 + per-point epilogue.
// Grid: NBLK blocks x 256 threads. Block handles ROWS consecutive rows of one
// batch. pt1[n] staged in LDS once per block (38.4 KB).
// Writes 6 partial sums per block:
//   [0] Sm   = sum dist_valid
//   [1] Sl2  = sum l2_min * dist_valid
//   [2] Ssl2 = sum (s1[argmin]+s0) * l2_min * dist_valid
//   [3] Ss   = sum (s1[argmin]+s0) * dist_valid
//   [4] Sv   = sum w_pt0_valid_mask
//   [5] Ssq  = sum (resampled - s0)^2 * w_pt0_valid_mask
// ---------------------------------------------------------------------------
__global__ __launch_bounds__(256) void s2ld_main_kernel(
    const float* __restrict__ w_pt0,    // [NB][L0][2]
    const float* __restrict__ pt1,      // [NB][L1][2]
    const void*  __restrict__ maskp,    // [NB][L0] (format per flag)
    const float* __restrict__ score0,   // [NB][L0]
    const float* __restrict__ score1,   // [NB][L1]
    const float* __restrict__ scale0,   // [NB][2]
    const float* __restrict__ scale1,   // [NB][2]
    const int*   __restrict__ flag,
    float*       __restrict__ partials) // [6][NBLK]
{
    __shared__ float2 spt[L1];
    __shared__ float  redd[ROWS * 4];
    __shared__ int    redj[ROWS * 4];

    const int blk  = blockIdx.x;
    const int rpb  = L0 / ROWS;               // rows-of-8 per batch
    const int n    = blk / rpb;
    const int i0   = (blk % rpb) * ROWS;

    // stage pt1[n] into LDS
    const float2* p1 = (const float2*)(pt1 + (size_t)n * L1 * 2);
    for (int j = threadIdx.x; j < L1; j += 256) spt[j] = p1[j];
    __syncthreads();

    // the 8 query points for this block
    float px[ROWS], py[ROWS];
    const float2* p0 = (const float2*)(w_pt0 + ((size_t)n * L0 + i0) * 2);
    #pragma unroll
    for (int r = 0; r < ROWS; ++r) { float2 q = p0[r]; px[r] = q.x; py[r] = q.y; }

    float bd[ROWS];
    int   bj[ROWS];
    #pragma unroll
    for (int r = 0; r < ROWS; ++r) { bd[r] = 3.0e38f; bj[r] = 0x7fffffff; }

    for (int j = threadIdx.x; j < L1; j += 256) {
        float2 q = spt[j];
        #pragma unroll
        for (int r = 0; r < ROWS; ++r) {
            float dx = px[r] - q.x;
            float dy = py[r] - q.y;
            float d2 = dx * dx + dy * dy;
            if (d2 < bd[r]) { bd[r] = d2; bj[r] = j; }  // ascending j => first occurrence
        }
    }

    // wave-level (64-lane) min+argmin reduce, tie-break to smaller j
    const int lane = threadIdx.x & 63;
    const int wv   = threadIdx.x >> 6;
    #pragma unroll
    for (int r = 0; r < ROWS; ++r) {
        float d  = bd[r];
        int   jj = bj[r];
        #pragma unroll
        for (int off = 32; off; off >>= 1) {
            float od = __shfl_xor(d, off);
            int   oj = __shfl_xor(jj, off);
            if (od < d || (od == d && oj < jj)) { d = od; jj = oj; }
        }
        if (lane == 0) { redd[r * 4 + wv] = d; redj[r * 4 + wv] = jj; }
    }
    __syncthreads();

    if (threadIdx.x == 0) {
        const int fmt = *flag;
        const float thr = 8.0f * scale0[n * 2 + 0];
        const float W1  = (float)W1C * scale1[n * 2 + 0];
        const float H1  = (float)H1C * scale1[n * 2 + 1];
        const float sxd = (W1 * 8.0f - 1.0f) * 0.5f;   // (W1*8-1)/2
        const float syd = (H1 * 8.0f - 1.0f) * 0.5f;
        const float* im = score1 + (size_t)n * L1;     // [60][80]

        float Sm = 0.f, Sl2 = 0.f, Ssl2 = 0.f, Ss = 0.f, Sv = 0.f, Ssq = 0.f;

        for (int r = 0; r < ROWS; ++r) {
            // merge the 4 per-wave results
            float d  = redd[r * 4 + 0];
            int   jj = redj[r * 4 + 0];
            for (int w = 1; w < 4; ++w) {
                float od = redd[r * 4 + w];
                int   oj = redj[r * 4 + w];
                if (od < d || (od == d && oj < jj)) { d = od; jj = oj; }
            }
            const float l2 = sqrtf(d);
            const int gi = n * L0 + i0 + r;

            bool mk;
            if (fmt == 0)      mk = ((const int*)maskp)[gi] != 0;
            else if (fmt == 1) mk = ((const float*)maskp)[gi] != 0.0f;
            else               mk = ((const unsigned char*)maskp)[gi] != 0;
            const float mf = mk ? 1.0f : 0.0f;
            const float dv = (l2 <= thr) ? mf : 0.0f;

            const float s0  = score0[gi];
            const float s1a = im[jj];
            const float ssum = s1a + s0;

            Sm   += dv;
            Sl2  += l2 * dv;
            Ss   += ssum * dv;
            Ssl2 += ssum * l2 * dv;
            Sv   += mf;

            // bilinear grid-sample of score1 (as 60x80 image), zero outside
            const float nx = px[r] / sxd - 1.0f;
            const float ny = py[r] / syd - 1.0f;
            const float gx = (nx + 1.0f) * 0.5f * (float)(W1C - 1);
            const float gy = (ny + 1.0f) * 0.5f * (float)(H1C - 1);
            const float x0 = floorf(gx), y0 = floorf(gy);
            const float x1 = x0 + 1.0f,  y1 = y0 + 1.0f;
            const float wx1 = gx - x0, wx0 = 1.0f - wx1;
            const float wy1 = gy - y0, wy0 = 1.0f - wy1;

            auto corner = [&](float xf, float yf) -> float {
                bool inb = (xf >= 0.0f) && (xf <= (float)(W1C - 1)) &&
                           (yf >= 0.0f) && (yf <= (float)(H1C - 1));
                int xc = (int)fminf(fmaxf(xf, 0.0f), (float)(W1C - 1));
                int yc = (int)fminf(fmaxf(yf, 0.0f), (float)(H1C - 1));
                float v = im[yc * W1C + xc];
                return inb ? v : 0.0f;
            };

            const float res = corner(x0, y0) * wx0 * wy0
                            + corner(x1, y0) * wx1 * wy0
                            + corner(x0, y1) * wx0 * wy1
                            + corner(x1, y1) * wx1 * wy1;
            const float dsc = res - s0;
            Ssq += dsc * dsc * mf;
        }

        partials[0 * NBLK + blk] = Sm;
        partials[1 * NBLK + blk] = Sl2;
        partials[2 * NBLK + blk] = Ssl2;
        partials[3 * NBLK + blk] = Ss;
        partials[4 * NBLK + blk] = Sv;
        partials[5 * NBLK + blk] = Ssq;
    }
}

// ---------------------------------------------------------------------------
// Kernel 3: reduce the 6 partial arrays and emit the 3 outputs.
// ---------------------------------------------------------------------------
__global__ __launch_bounds__(256) void s2ld_finalize_kernel(
    const float* __restrict__ partials, float* __restrict__ out)
{
    __shared__ float red[6][4];
    for (int k = 0; k < 6; ++k) {
        float s = 0.0f;
        for (int r = threadIdx.x; r < NBLK; r += 256) s += partials[k * NBLK + r];
        #pragma unroll
        for (int off = 32; off; off >>= 1) s += __shfl_xor(s, off);
        if ((threadIdx.x & 63) == 0) red[k][threadIdx.x >> 6] = s;
    }
    __syncthreads();
    if (threadIdx.x == 0) {
        float S[6];
        #pragma unroll
        for (int k = 0; k < 6; ++k) S[k] = red[k][0] + red[k][1] + red[k][2] + red[k][3];
        const float denom = fmaxf(S[0], 1.0f);
        const float lm = S[1] / denom;                 // loc_loss_mean
        out[0] = lm;
        out[1] = (S[2] - lm * S[3]) / denom;           // rep_loss_mean
        out[2] = 2.0f * S[5] / fmaxf(S[4], 1.0f);      // score_loss
    }
}

extern "C" void kernel_launch(void* const* d_in, const int* in_sizes, int n_in,
                              void* d_out, int out_size, void* d_ws, size_t ws_size,
                              hipStream_t stream) {
    const float* w_pt0  = (const float*)d_in[0];
    const float* pt1    = (const float*)d_in[1];
    const void*  maskp  =               d_in[2];
    const float* score0 = (const float*)d_in[3];
    const float* score1 = (const float*)d_in[4];
    // d_in[5] = image1 (zeros, shape only) -- unused
    const float* scale0 = (const float*)d_in[6];
    const float* scale1 = (const float*)d_in[7];

    int*   flag     = (int*)d_ws;
    float* partials = (float*)((char*)d_ws + 256);

    detect_mask_kernel<<<1, 256, 0, stream>>>((const unsigned int*)maskp, flag);
    s2ld_main_kernel<<<NBLK, 256, 0, stream>>>(w_pt0, pt1, maskp, score0, score1,
                                               scale0, scale1, flag, partials);
    s2ld_finalize_kernel<<<1, 256, 0, stream>>>(partials, (float*)d_out);
}